// Round 3
// baseline (465.442 us; speedup 1.0000x reference)
//
#include <hip/hip_runtime.h>
#include <hip/hip_bf16.h>
#include <math.h>

#define NEG_SLOPE 0.2f

// ---------------- utility ----------------
__global__ __launch_bounds__(256) void zero_int_kernel(int* __restrict__ p, int n) {
    int i = blockIdx.x * 256 + threadIdx.x;
    if (i < n) p[i] = 0;
}

// ---------------- CSR build ----------------
__global__ __launch_bounds__(256) void count_deg_kernel(const int* __restrict__ dst,
                                                        int E, int N, int* __restrict__ deg) {
    int e = blockIdx.x * 256 + threadIdx.x;
    int Etot = E + N;
    if (e >= Etot) return;
    int d = (e < E) ? dst[e] : (e - E);
    atomicAdd(&deg[d], 1);
}

__global__ __launch_bounds__(1024) void scan_kernel(const int* __restrict__ deg,
                                                    int* __restrict__ row_ptr, int N) {
    __shared__ int part[1024];
    int t = threadIdx.x;
    int chunk = (N + 1023) >> 10;
    int b = t * chunk;
    int e = b + chunk; if (e > N) e = N;
    int sum = 0;
    for (int i = b; i < e; ++i) sum += deg[i];
    part[t] = sum;
    __syncthreads();
    for (int off = 1; off < 1024; off <<= 1) {
        int v = (t >= off) ? part[t - off] : 0;
        __syncthreads();
        part[t] += v;
        __syncthreads();
    }
    int run = (t == 0) ? 0 : part[t - 1];
    for (int i = b; i < e; ++i) { row_ptr[i] = run; run += deg[i]; }
    if (t == 1023) row_ptr[N] = part[1023];
}

__global__ __launch_bounds__(256) void scatter_kernel(const int* __restrict__ src,
                                                      const int* __restrict__ dst,
                                                      int E, int N,
                                                      const int* __restrict__ row_ptr,
                                                      int* __restrict__ cursor,
                                                      int* __restrict__ col_src) {
    int e = blockIdx.x * 256 + threadIdx.x;
    int Etot = E + N;
    if (e >= Etot) return;
    int d, s;
    if (e < E) { d = dst[e]; s = src[e]; } else { d = e - E; s = e - E; }
    int pos = atomicAdd(&cursor[d], 1);
    col_src[row_ptr[d] + pos] = s;
}

// ---------------- GEMM: Y[N,128] = X[N,128] @ W[128,128] ----------------
__global__ __launch_bounds__(256) void gemm_xw_kernel(const float* __restrict__ X,
                                                      const float* __restrict__ W,
                                                      float* __restrict__ Y, int N) {
    __shared__ float Ws[128 * 128];
    int tid = threadIdx.x;
    {
        const float4* W4 = (const float4*)W;
        float4* Ws4 = (float4*)Ws;
        #pragma unroll
        for (int i = 0; i < 16; ++i) Ws4[tid + i * 256] = W4[tid + i * 256];
    }
    __syncthreads();
    int r = blockIdx.x * 64 + (tid >> 2);
    int c0 = (tid & 3) * 32;
    if (r >= N) return;
    float acc[32];
    #pragma unroll
    for (int j = 0; j < 32; ++j) acc[j] = 0.f;
    const float4* Xrow = (const float4*)(X + (size_t)r * 128);
    for (int k4 = 0; k4 < 32; ++k4) {
        float4 xv = Xrow[k4];
        #pragma unroll
        for (int kk = 0; kk < 4; ++kk) {
            float xk = (kk == 0) ? xv.x : (kk == 1) ? xv.y : (kk == 2) ? xv.z : xv.w;
            const float4* wrow = (const float4*)(Ws + (k4 * 4 + kk) * 128 + c0);
            #pragma unroll
            for (int j4 = 0; j4 < 8; ++j4) {
                float4 wv = wrow[j4];
                acc[j4 * 4 + 0] = fmaf(xk, wv.x, acc[j4 * 4 + 0]);
                acc[j4 * 4 + 1] = fmaf(xk, wv.y, acc[j4 * 4 + 1]);
                acc[j4 * 4 + 2] = fmaf(xk, wv.z, acc[j4 * 4 + 2]);
                acc[j4 * 4 + 3] = fmaf(xk, wv.w, acc[j4 * 4 + 3]);
            }
        }
    }
    float4* Yrow = (float4*)(Y + (size_t)r * 128 + c0);
    #pragma unroll
    for (int j4 = 0; j4 < 8; ++j4)
        Yrow[j4] = make_float4(acc[j4 * 4 + 0], acc[j4 * 4 + 1], acc[j4 * 4 + 2], acc[j4 * 4 + 3]);
}

// ---------------- attention dots, layer 1 (H=8, C=16) ----------------
__global__ __launch_bounds__(256) void attdot1_kernel(const float* __restrict__ xh,
                                                      const float* __restrict__ attS,
                                                      const float* __restrict__ attD,
                                                      float* __restrict__ asrc,
                                                      float* __restrict__ adst, int N) {
    int node = blockIdx.x * 4 + (threadIdx.x >> 6);
    int lane = threadIdx.x & 63;
    if (node >= N) return;
    const float* row = xh + (size_t)node * 128;
    float x1 = row[lane], x2 = row[lane + 64];
    float s1 = x1 * attS[lane], s2 = x2 * attS[lane + 64];
    float d1 = x1 * attD[lane], d2 = x2 * attD[lane + 64];
    #pragma unroll
    for (int off = 8; off >= 1; off >>= 1) {
        s1 += __shfl_xor(s1, off, 64);
        s2 += __shfl_xor(s2, off, 64);
        d1 += __shfl_xor(d1, off, 64);
        d2 += __shfl_xor(d2, off, 64);
    }
    if ((lane & 15) == 0) {
        int h = lane >> 4;
        asrc[node * 8 + h]     = s1;
        asrc[node * 8 + h + 4] = s2;
        adst[node * 8 + h]     = d1;
        adst[node * 8 + h + 4] = d2;
    }
}

// ---------------- attention dots, layer 2 (H=1, C=128) ----------------
__global__ __launch_bounds__(256) void attdot2_kernel(const float* __restrict__ xh,
                                                      const float* __restrict__ attS,
                                                      const float* __restrict__ attD,
                                                      float* __restrict__ asrc,
                                                      float* __restrict__ adst, int N) {
    int node = blockIdx.x * 4 + (threadIdx.x >> 6);
    int lane = threadIdx.x & 63;
    if (node >= N) return;
    const float* row = xh + (size_t)node * 128;
    float x1 = row[lane], x2 = row[lane + 64];
    float ts = x1 * attS[lane] + x2 * attS[lane + 64];
    float td = x1 * attD[lane] + x2 * attD[lane + 64];
    #pragma unroll
    for (int off = 32; off >= 1; off >>= 1) {
        ts += __shfl_xor(ts, off, 64);
        td += __shfl_xor(td, off, 64);
    }
    if (lane == 0) { asrc[node] = ts; adst[node] = td; }
}

// ---------------- layer-1 aggregation: online softmax, one wave per node ----------------
__global__ __launch_bounds__(256) void agg1_kernel(const float* __restrict__ xh,
                                                   const float* __restrict__ asrc,
                                                   const float* __restrict__ adst,
                                                   const int* __restrict__ row_ptr,
                                                   const int* __restrict__ col_src,
                                                   const float* __restrict__ b1,
                                                   float* __restrict__ out, int N) {
    int node = blockIdx.x * 4 + (threadIdx.x >> 6);
    int lane = threadIdx.x & 63;
    if (node >= N) return;
    int h1 = lane >> 4;                 // head of value v1=lane; v2=lane+64 -> head h1+4
    float ad1 = adst[node * 8 + h1];
    float ad2 = adst[node * 8 + h1 + 4];
    int beg = row_ptr[node], end = row_ptr[node + 1];
    float m1 = -INFINITY, m2 = -INFINITY;
    float s1 = 0.f, s2 = 0.f, a1 = 0.f, a2 = 0.f;
    for (int e = beg; e < end; ++e) {
        int sv = col_src[e];
        float e1 = asrc[sv * 8 + h1] + ad1;
        float e2 = asrc[sv * 8 + h1 + 4] + ad2;
        e1 = (e1 > 0.f) ? e1 : NEG_SLOPE * e1;
        e2 = (e2 > 0.f) ? e2 : NEG_SLOPE * e2;
        float x1 = xh[(size_t)sv * 128 + lane];
        float x2 = xh[(size_t)sv * 128 + lane + 64];
        if (e1 > m1) { float r = __expf(m1 - e1); s1 *= r; a1 *= r; m1 = e1; }
        float p1 = __expf(e1 - m1);
        s1 += p1; a1 = fmaf(p1, x1, a1);
        if (e2 > m2) { float r = __expf(m2 - e2); s2 *= r; a2 *= r; m2 = e2; }
        float p2 = __expf(e2 - m2);
        s2 += p2; a2 = fmaf(p2, x2, a2);
    }
    float o1 = a1 / s1 + b1[lane];
    float o2 = a2 / s2 + b1[lane + 64];
    // ELU
    o1 = (o1 > 0.f) ? o1 : (__expf(o1) - 1.f);
    o2 = (o2 > 0.f) ? o2 : (__expf(o2) - 1.f);
    out[(size_t)node * 128 + lane]      = o1;
    out[(size_t)node * 128 + lane + 64] = o2;
}

// ---------------- layer-2 aggregation (H=1) ----------------
__global__ __launch_bounds__(256) void agg2_kernel(const float* __restrict__ xh,
                                                   const float* __restrict__ asrc,
                                                   const float* __restrict__ adst,
                                                   const int* __restrict__ row_ptr,
                                                   const int* __restrict__ col_src,
                                                   const float* __restrict__ b2,
                                                   float* __restrict__ out, int N) {
    int node = blockIdx.x * 4 + (threadIdx.x >> 6);
    int lane = threadIdx.x & 63;
    if (node >= N) return;
    float ad = adst[node];
    int beg = row_ptr[node], end = row_ptr[node + 1];
    float m = -INFINITY, s = 0.f, a1 = 0.f, a2 = 0.f;
    for (int e = beg; e < end; ++e) {
        int sv = col_src[e];
        float al = asrc[sv] + ad;
        al = (al > 0.f) ? al : NEG_SLOPE * al;
        float x1 = xh[(size_t)sv * 128 + lane];
        float x2 = xh[(size_t)sv * 128 + lane + 64];
        if (al > m) { float r = __expf(m - al); s *= r; a1 *= r; a2 *= r; m = al; }
        float p = __expf(al - m);
        s += p;
        a1 = fmaf(p, x1, a1);
        a2 = fmaf(p, x2, a2);
    }
    out[(size_t)node * 128 + lane]      = a1 / s + b2[lane];
    out[(size_t)node * 128 + lane + 64] = a2 / s + b2[lane + 64];
}

// ---------------- launch ----------------
extern "C" void kernel_launch(void* const* d_in, const int* in_sizes, int n_in,
                              void* d_out, int out_size, void* d_ws, size_t ws_size,
                              hipStream_t stream) {
    const float* x        = (const float*)d_in[0];
    const int*   src      = (const int*)d_in[1];
    const int*   dst      = (const int*)d_in[2];
    const float* W1       = (const float*)d_in[3];
    const float* att_src1 = (const float*)d_in[4];
    const float* att_dst1 = (const float*)d_in[5];
    const float* b1       = (const float*)d_in[6];
    const float* W2       = (const float*)d_in[7];
    const float* att_src2 = (const float*)d_in[8];
    const float* att_dst2 = (const float*)d_in[9];
    const float* b2       = (const float*)d_in[10];

    const int N = in_sizes[0] / 128;
    const int E = in_sizes[1];
    const int Etot = E + N;

    float* fws   = (float*)d_ws;
    float* xh    = fws;                    // N*128 (reused for both layers)
    float* asrc1 = xh + (size_t)N * 128;   // N*8
    float* adst1 = asrc1 + (size_t)N * 8;  // N*8
    float* asrc2 = adst1 + (size_t)N * 8;  // N
    float* adst2 = asrc2 + N;              // N
    int*   deg     = (int*)(adst2 + N);    // N
    int*   cursor  = deg + N;              // N
    int*   row_ptr = cursor + N;           // N+1
    int*   col_src = row_ptr + N + 1;      // Etot

    float* h = (float*)d_out;              // layer-1 output lives in d_out

    const int nodeBlocks = (N + 3) / 4;
    const int edgeBlocks = (Etot + 255) / 256;
    const int gemmBlocks = (N + 63) / 64;

    // CSR build (shared by both layers)
    zero_int_kernel<<<(2 * N + 255) / 256, 256, 0, stream>>>(deg, 2 * N);
    count_deg_kernel<<<edgeBlocks, 256, 0, stream>>>(dst, E, N, deg);
    scan_kernel<<<1, 1024, 0, stream>>>(deg, row_ptr, N);
    scatter_kernel<<<edgeBlocks, 256, 0, stream>>>(src, dst, E, N, row_ptr, cursor, col_src);

    // Layer 1
    gemm_xw_kernel<<<gemmBlocks, 256, 0, stream>>>(x, W1, xh, N);
    attdot1_kernel<<<nodeBlocks, 256, 0, stream>>>(xh, att_src1, att_dst1, asrc1, adst1, N);
    agg1_kernel<<<nodeBlocks, 256, 0, stream>>>(xh, asrc1, adst1, row_ptr, col_src, b1, h, N);

    // Layer 2
    gemm_xw_kernel<<<gemmBlocks, 256, 0, stream>>>(h, W2, xh, N);
    attdot2_kernel<<<nodeBlocks, 256, 0, stream>>>(xh, att_src2, att_dst2, asrc2, adst2, N);
    agg2_kernel<<<nodeBlocks, 256, 0, stream>>>(xh, asrc2, adst2, row_ptr, col_src, b2, (float*)d_out, N);
}